// Round 3
// baseline (2506.064 us; speedup 1.0000x reference)
//
#include <hip/hip_runtime.h>
#include <hip/hip_bf16.h>

#define CUT 10
#define NB 256
#define NLAYERS 4
#define WSTRIDE 48

// slot map (each slot = padded 10x10 complex, 100 float2)
#define SLOT_S0 0
#define SLOT_DM 1      // 1024 displacement-prep matrices
#define SLOT_SQ 1025   // 16 squeezers (l*4+m)
#define SLOT_DS 1041   // 16 displacements (l*4+m)
#define SLOT_BS 1057   // 48 gates * 19 photon-number blocks
#define NSLOTS  1969

typedef __hip_bfloat16 bf16;

// read element i of a buffer whose dtype (f32 vs bf16) was sniffed at runtime
__device__ __forceinline__ float readv(const void* p, int i, int isf32) {
  if (isf32) return ((const float*)p)[i];
  return __bfloat162float(((const bf16*)p)[i]);
}

// ------------------- K0: sniff input dtype -------------------
// f32 data reinterpreted as bf16 halves has random exponent bits in the even
// halves -> values > 1000 or non-finite with certainty over >=512 halves.
// Genuine bf16 data here is all |v| < 2.
__global__ void sniff_dtype(const void* p, int n_elems, int* flag) {
  __shared__ float red[256];
  const unsigned short* h = (const unsigned short*)p;
  int t = threadIdx.x;
  float mx = 0.f;
  for (int i = t; i < n_elems; i += 256) {
    unsigned short u = h[i];
    bf16 bv = *(const bf16*)&u;
    float v = fabsf(__bfloat162float(bv));
    if (!(v < 1e30f)) v = 1e30f;   // NaN/Inf -> big
    mx = fmaxf(mx, v);
  }
  red[t] = mx;
  __syncthreads();
  for (int off = 128; off > 0; off >>= 1) {
    if (t < off) red[t] = fmaxf(red[t], red[t + off]);
    __syncthreads();
  }
  if (t == 0) *flag = (red[0] > 1000.f) ? 1 : 0;  // 1 => buffer is really f32
}

// ------------------- K1: build all generators -------------------
__global__ void build_gens(float2* slots, const void* inp, const void* w,
                           const int* flag) {
  int s = blockIdx.x;
  int t = threadIdx.x;
  if (t >= 100) return;
  int isf32 = *flag;
  int i = t / 10, j = t % 10;
  float2 val = make_float2(0.f, 0.f);
  if (s == SLOT_S0) {
    // -0.25i (a^2 + adag^2)   [z=0.5i in reference]
    if (j == i + 2)      { float c = sqrtf((float)((i+1)*(i+2))); val.y = -0.25f*c; }
    else if (i == j + 2) { float c = sqrtf((float)((j+1)*(j+2))); val.y = -0.25f*c; }
  } else if (s < SLOT_SQ) {
    // r (adag - a), r = inputs[k]
    int k = s - SLOT_DM;
    float r = readv(inp, k, isf32);
    if (i == j + 1)      val.x =  r * sqrtf((float)(j+1));
    else if (j == i + 1) val.x = -r * sqrtf((float)(i+1));
  } else if (s < SLOT_DS) {
    // 0.5 r (a^2 - adag^2)
    int k = s - SLOT_SQ; int l = k >> 2; int m = k & 3;
    float r = readv(w, l*WSTRIDE + 16 + m, isf32);
    if (j == i + 2)      val.x =  0.5f*r*sqrtf((float)((i+1)*(i+2)));
    else if (i == j + 2) val.x = -0.5f*r*sqrtf((float)((j+1)*(j+2)));
  } else if (s < SLOT_BS) {
    // alpha adag - conj(alpha) a,  alpha = rd e^{i phd}
    int k = s - SLOT_DS; int l = k >> 2; int m = k & 3;
    float rd = readv(w, l*WSTRIDE + 36 + m, isf32);
    float ph = readv(w, l*WSTRIDE + 40 + m, isf32);
    float ar = rd * cosf(ph), ai = rd * sinf(ph);
    if (i == j + 1)      { float c = sqrtf((float)(j+1)); val.x =  ar*c; val.y = ai*c; }
    else if (j == i + 1) { float c = sqrtf((float)(i+1)); val.x = -ar*c; val.y = ai*c; }
  } else {
    // BS block N of gate g: tridiagonal t(e^{ip} raise_i lower_j - h.c.)
    int rel = s - SLOT_BS;
    int g = rel / 19; int N = rel % 19;
    int l = g / 12; int h = (g % 12) / 6; int p = g % 6;
    float th = readv(w, l*WSTRIDE + (h ? 20 : 0) + p, isf32);
    float ph = readv(w, l*WSTRIDE + (h ? 26 : 6) + p, isf32);
    int lo = max(0, N - 9), hi = min(9, N);
    int d = hi - lo + 1;
    if (i < d && j < d) {
      if (i == j + 1) {          // (k+1,k) = t e^{ip} c_k, k=j  [adag_i ⊗ a_j block]
        float c = sqrtf((float)((lo + j + 1) * (N - lo - j)));
        val.x = th * cosf(ph) * c; val.y = th * sinf(ph) * c;
      } else if (j == i + 1) {   // (k,k+1) = -t e^{-ip} c_k, k=i
        float c = sqrtf((float)((lo + i + 1) * (N - lo - i)));
        val.x = -th * cosf(ph) * c; val.y = th * sinf(ph) * c;
      }
    }
  }
  slots[(size_t)s * 100 + t] = val;
}

// ------------------- K2: generic expm (scaling-squaring + Taylor) -------------------
__global__ void expm_all(float2* slots) {
  __shared__ float2 T[100], P[100], R[100];
  __shared__ float rowsum[10];
  __shared__ int sshift;
  int s = blockIdx.x, t = threadIdx.x;
  int i = t / 10, j = t % 10;
  float2* G = slots + (size_t)s * 100;
  if (t < 100) T[t] = G[t];
  __syncthreads();
  if (t < 10) {
    float sum = 0.f;
    for (int c = 0; c < 10; ++c) { float2 z = T[t*10+c]; sum += fabsf(z.x) + fabsf(z.y); }
    rowsum[t] = sum;
  }
  __syncthreads();
  if (t == 0) {
    float nm = 0.f;
    for (int r = 0; r < 10; ++r) nm = fmaxf(nm, rowsum[r]);
    int sc = 0;
    if (!(nm < 1e6f)) sc = 0;           // NaN/Inf guard -> no hang
    else if (nm > 0.25f) sc = (int)ceilf(log2f(nm * 4.f));
    sshift = min(max(sc, 0), 40);       // hard clamp
  }
  __syncthreads();
  int sh = sshift;
  float scl = ldexpf(1.f, -sh);
  if (t < 100) {
    float2 z = T[t]; z.x *= scl; z.y *= scl;
    T[t] = z; P[t] = z;
    R[t] = make_float2(z.x + (i == j ? 1.f : 0.f), z.y);
  }
  __syncthreads();
  for (int k = 2; k <= 12; ++k) {
    float2 acc = make_float2(0.f, 0.f);
    if (t < 100) {
      for (int c = 0; c < 10; ++c) {
        float2 a = P[i*10+c], b = T[c*10+j];
        acc.x += a.x*b.x - a.y*b.y;
        acc.y += a.x*b.y + a.y*b.x;
      }
      float inv = 1.f / (float)k;
      acc.x *= inv; acc.y *= inv;
    }
    __syncthreads();
    if (t < 100) { P[t] = acc; R[t].x += acc.x; R[t].y += acc.y; }
    __syncthreads();
  }
  for (int q = 0; q < sh; ++q) {
    float2 acc = make_float2(0.f, 0.f);
    if (t < 100) {
      for (int c = 0; c < 10; ++c) {
        float2 a = R[i*10+c], b = R[c*10+j];
        acc.x += a.x*b.x - a.y*b.y;
        acc.y += a.x*b.y + a.y*b.x;
      }
    }
    __syncthreads();
    if (t < 100) R[t] = acc;
    __syncthreads();
  }
  if (t < 100) G[t] = R[t];
}

// ------------------- K3: initial product state -------------------
__global__ __launch_bounds__(256) void init_state(float2* state, const float2* slots) {
  __shared__ float2 psi0s[10];
  __shared__ float2 psi[4][10];
  int b = blockIdx.x, t = threadIdx.x;
  if (t < 10) psi0s[t] = slots[(size_t)t * 10];  // S0 column 0 (row t, col 0)
  __syncthreads();
  if (t < 40) {
    int m = t / 10, r = t % 10;
    const float2* Dm = slots + (size_t)(SLOT_DM + b*4 + m) * 100;
    float2 acc = make_float2(0.f, 0.f);
    for (int c = 0; c < 10; ++c) {
      float2 a = Dm[r*10+c], v = psi0s[c];
      acc.x += a.x*v.x - a.y*v.y;
      acc.y += a.x*v.y + a.y*v.x;
    }
    psi[m][r] = acc;
  }
  __syncthreads();
  float2* st = state + (size_t)b * 10000;
  for (int e = t; e < 10000; e += 256) {
    int n0 = e / 1000;
    float2 z = psi[0][n0];
    float2 w1 = psi[1][(e/100) % 10];
    float2 r1 = make_float2(z.x*w1.x - z.y*w1.y, z.x*w1.y + z.y*w1.x);
    float2 w2 = psi[2][(e/10) % 10];
    float2 r2 = make_float2(r1.x*w2.x - r1.y*w2.y, r1.x*w2.y + r1.y*w2.x);
    float2 w3 = psi[3][e % 10];
    float2 r3 = make_float2(r2.x*w3.x - r2.y*w3.y, r2.x*w3.y + r2.y*w3.x);
    st[e] = r3;
  }
}

// ------------------- K4: two-mode (beamsplitter) apply, block-diagonal -------------------
__global__ __launch_bounds__(256) void bs_apply(
    float2* state, const float2* slots, int slotbase,
    int mulB, int mul0, int mul1, int mul2, int p1, int p2,
    int strI, int strJ, const void* pcoef, const int* flag,
    int modeB, int mode0, int mode1, int mode2)
{
  int b = blockIdx.x, a0 = (int)blockIdx.y, t = threadIdx.x;
  float2* st = state + (size_t)b * 10000;
  float cB = 0.f, c0 = 0.f, c1 = 0.f, c2 = 0.f;
  if (pcoef) {
    int isf32 = *flag;
    cB = readv(pcoef, modeB, isf32); c0 = readv(pcoef, mode0, isf32);
    c1 = readv(pcoef, mode1, isf32); c2 = readv(pcoef, mode2, isf32);
  }
  float2 outv[4];
  int eidx[4];
#pragma unroll
  for (int it = 0; it < 4; ++it) {
    int idx = it*256 + t;
    eidx[it] = -1;
    if (idx < 1000) {
      int d0 = idx % 10; int r2i = idx / 10; int d1 = r2i % 10; int d2 = r2i / 10;
      int m1 = (p1 == 0) ? d0 : (p1 == 1) ? d1 : d2;
      int m2 = (p2 == 0) ? d0 : (p2 == 1) ? d1 : d2;
      int e = a0*mulB + d0*mul0 + d1*mul1 + d2*mul2;
      int N = m1 + m2;
      int lo = max(0, N-9), hi = min(9, N);
      const float2* U = slots + (size_t)(slotbase + N) * 100;
      int base = e - m1*strI - m2*strJ;
      int rr = m1 - lo;
      float2 acc = make_float2(0.f, 0.f);
      for (int n1 = lo; n1 <= hi; ++n1) {
        float2 u = U[rr*10 + (n1 - lo)];
        float2 sv = st[base + n1*strI + (N - n1)*strJ];
        acc.x += u.x*sv.x - u.y*sv.y;
        acc.y += u.x*sv.y + u.y*sv.x;
      }
      if (pcoef) {  // fused linear phase diag exp(i sum vph_m n_m)
        float ang = cB*(float)a0 + c0*(float)d0 + c1*(float)d1 + c2*(float)d2;
        float sn, cs; sincosf(ang, &sn, &cs);
        float2 r = make_float2(acc.x*cs - acc.y*sn, acc.x*sn + acc.y*cs);
        acc = r;
      }
      outv[it] = acc; eidx[it] = e;
    }
  }
  __syncthreads();  // all reads drained before any in-place write (block-private slice)
#pragma unroll
  for (int it = 0; it < 4; ++it)
    if (eidx[it] >= 0) st[eidx[it]] = outv[it];
}

// ------------------- K5: single-mode apply (squeeze/displace), optional phase fuse -------------------
__global__ __launch_bounds__(256) void single_apply(
    float2* state, const float2* slots, int slot,
    int mulB, int mul0, int mul1, int mul2, int actSlot, int strM,
    const void* pcoef, const int* flag, int pmode,
    int modeB, int mode0, int mode1, int mode2)
{
  int b = blockIdx.x, a0 = (int)blockIdx.y, t = threadIdx.x;
  float2* st = state + (size_t)b * 10000;
  const float2* U = slots + (size_t)slot * 100;
  float cB = 0.f, c0 = 0.f, c1 = 0.f, c2 = 0.f;
  if (pcoef) {
    int isf32 = *flag;
    cB = readv(pcoef, modeB, isf32); c0 = readv(pcoef, mode0, isf32);
    c1 = readv(pcoef, mode1, isf32); c2 = readv(pcoef, mode2, isf32);
  }
  float2 outv[4];
  int eidx[4];
#pragma unroll
  for (int it = 0; it < 4; ++it) {
    int idx = it*256 + t;
    eidx[it] = -1;
    if (idx < 1000) {
      int d0 = idx % 10; int r2i = idx / 10; int d1 = r2i % 10; int d2 = r2i / 10;
      int act = (actSlot == 0) ? d0 : (actSlot == 1) ? d1 : d2;
      int e = a0*mulB + d0*mul0 + d1*mul1 + d2*mul2;
      int base = e - act*strM;
      float2 acc = make_float2(0.f, 0.f);
      for (int n = 0; n < 10; ++n) {
        float2 u = U[act*10 + n];
        float2 sv = st[base + n*strM];
        acc.x += u.x*sv.x - u.y*sv.y;
        acc.y += u.x*sv.y + u.y*sv.x;
      }
      if (pmode) {  // pmode 1: linear (vph), pmode 2: Kerr (n^2)
        float fB = (float)a0, f0 = (float)d0, f1 = (float)d1, f2 = (float)d2;
        if (pmode == 2) { fB *= fB; f0 *= f0; f1 *= f1; f2 *= f2; }
        float ang = cB*fB + c0*f0 + c1*f1 + c2*f2;
        float sn, cs; sincosf(ang, &sn, &cs);
        float2 r = make_float2(acc.x*cs - acc.y*sn, acc.x*sn + acc.y*cs);
        acc = r;
      }
      outv[it] = acc; eidx[it] = e;
    }
  }
  __syncthreads();
#pragma unroll
  for (int it = 0; it < 4; ++it)
    if (eidx[it] >= 0) st[eidx[it]] = outv[it];
}

// ------------------- K6: photon-number expectations (f32 output) -------------------
__global__ __launch_bounds__(256) void reduce_out(const float2* state, float* out) {
  __shared__ float red[256];
  int b = blockIdx.x, t = threadIdx.x;
  const float2* st = state + (size_t)b * 10000;
  float acc[4] = {0.f, 0.f, 0.f, 0.f};
  for (int e = t; e < 10000; e += 256) {
    float2 z = st[e];
    float p = z.x*z.x + z.y*z.y;
    int n3 = e % 10, n2 = (e/10) % 10, n1 = (e/100) % 10, n0 = e / 1000;
    acc[0] += p*(float)n0; acc[1] += p*(float)n1;
    acc[2] += p*(float)n2; acc[3] += p*(float)n3;
  }
  for (int m = 0; m < 4; ++m) {
    red[t] = acc[m];
    __syncthreads();
    for (int off = 128; off > 0; off >>= 1) {
      if (t < off) red[t] += red[t + off];
      __syncthreads();
    }
    if (t == 0) out[b*4 + m] = red[0];
    __syncthreads();
  }
}

extern "C" void kernel_launch(void* const* d_in, const int* in_sizes, int n_in,
                              void* d_out, int out_size, void* d_ws, size_t ws_size,
                              hipStream_t stream) {
  const void* inp = d_in[0];
  const void* w   = d_in[1];
  float* out = (float*)d_out;           // reference output dtype is float32
  int*    flag  = (int*)d_ws;           // 16-byte header
  float2* slots = (float2*)((char*)d_ws + 16);
  float2* state = slots + (size_t)NSLOTS * 100;

  sniff_dtype<<<dim3(1), dim3(256), 0, stream>>>(inp, in_sizes[0], flag);
  build_gens<<<dim3(NSLOTS), dim3(128), 0, stream>>>(slots, inp, w, flag);
  expm_all<<<dim3(NSLOTS), dim3(128), 0, stream>>>(slots);
  init_state<<<dim3(NB), dim3(256), 0, stream>>>(state, slots);

  // per-pair index configs: digit slots ordered stride-ascending for coalescing;
  // blockIdx.y carries the largest-stride spectator digit.
  struct BSCfg { int mulB, mul0, mul1, mul2, p1, p2, strI, strJ, modeB, mode0, mode1, mode2; };
  static const BSCfg bs[6] = {
    {10,   1, 100, 1000, 2, 1, 1000, 100, 2, 3, 1, 0},  // (0,1)
    {100,  1, 10,  1000, 2, 1, 1000, 10,  1, 3, 2, 0},  // (0,2)
    {100,  1, 10,  1000, 2, 0, 1000, 1,   1, 3, 2, 0},  // (0,3)
    {1000, 1, 10,  100,  2, 1, 100,  10,  0, 3, 2, 1},  // (1,2)
    {1000, 1, 10,  100,  2, 0, 100,  1,   0, 3, 2, 1},  // (1,3)
    {1000, 1, 10,  100,  1, 0, 10,   1,   0, 3, 2, 1},  // (2,3)
  };
  struct SMCfg { int mulB, mul0, mul1, mul2, act, strM, modeB, mode0, mode1, mode2; };
  static const SMCfg sm[4] = {
    {100,  1, 10, 1000, 2, 1000, 1, 3, 2, 0},  // mode 0
    {1000, 1, 10, 100,  2, 100,  0, 3, 2, 1},  // mode 1
    {1000, 1, 10, 100,  1, 10,   0, 3, 2, 1},  // mode 2
    {1000, 1, 10, 100,  0, 1,    0, 3, 2, 1},  // mode 3
  };

  dim3 grid(NB, 10), blk(256);
  for (int l = 0; l < NLAYERS; ++l) {
    for (int half = 0; half < 2; ++half) {
      for (int p = 0; p < 6; ++p) {
        int g = l*12 + half*6 + p;
        const BSCfg& c = bs[p];
        if (p == 5) {
          // fuse the interferometer's vph diag into the last BS gate's output;
          // phase coefficient for mode m lives at w[off + m]
          int off = l*WSTRIDE + (half ? 32 : 12);
          bs_apply<<<grid, blk, 0, stream>>>(state, slots, SLOT_BS + g*19,
              c.mulB, c.mul0, c.mul1, c.mul2, c.p1, c.p2, c.strI, c.strJ,
              w, flag, off + c.modeB, off + c.mode0, off + c.mode1, off + c.mode2);
        } else {
          bs_apply<<<grid, blk, 0, stream>>>(state, slots, SLOT_BS + g*19,
              c.mulB, c.mul0, c.mul1, c.mul2, c.p1, c.p2, c.strI, c.strJ,
              nullptr, flag, 0, 0, 0, 0);
        }
      }
      for (int m = 0; m < 4; ++m) {
        const SMCfg& c = sm[m];
        int slot = (half == 0) ? (SLOT_SQ + l*4 + m) : (SLOT_DS + l*4 + m);
        if (half == 1 && m == 3) {   // fuse Kerr diag exp(i sum kap_m n_m^2)
          int off = l*WSTRIDE + 44;
          single_apply<<<grid, blk, 0, stream>>>(state, slots, slot,
              c.mulB, c.mul0, c.mul1, c.mul2, c.act, c.strM,
              w, flag, 2, off + c.modeB, off + c.mode0, off + c.mode1, off + c.mode2);
        } else {
          single_apply<<<grid, blk, 0, stream>>>(state, slots, slot,
              c.mulB, c.mul0, c.mul1, c.mul2, c.act, c.strM,
              nullptr, flag, 0, 0, 0, 0, 0);
        }
      }
    }
  }
  reduce_out<<<dim3(NB), blk, 0, stream>>>(state, out);
}

// Round 4
// 715.025 us; speedup vs baseline: 3.5049x; 3.5049x over previous
//
#include <hip/hip_runtime.h>
#include <hip/hip_bf16.h>

#define CUT 10
#define NB 256
#define NLAYERS 4
#define WSTRIDE 48

// slot map (each slot = padded 10x10 complex, 100 float2)
#define SLOT_S0 0
#define SLOT_DM 1      // 1024 displacement-prep matrices
#define SLOT_SQ 1025   // 16 squeezers (l*4+m)
#define SLOT_DS 1041   // 16 displacements (l*4+m)
#define SLOT_BS 1057   // 48 gates * 19 photon-number blocks
#define NSLOTS  1969

typedef __hip_bfloat16 bf16;

// read element i of a buffer whose dtype (f32 vs bf16) was sniffed at runtime
__device__ __forceinline__ float readv(const void* p, int i, int isf32) {
  if (isf32) return ((const float*)p)[i];
  return __bfloat162float(((const bf16*)p)[i]);
}

// ------------------- K0: sniff input dtype -------------------
__global__ void sniff_dtype(const void* p, int n_elems, int* flag) {
  __shared__ float red[256];
  const unsigned short* h = (const unsigned short*)p;
  int t = threadIdx.x;
  float mx = 0.f;
  for (int i = t; i < n_elems; i += 256) {
    unsigned short u = h[i];
    bf16 bv = *(const bf16*)&u;
    float v = fabsf(__bfloat162float(bv));
    if (!(v < 1e30f)) v = 1e30f;
    mx = fmaxf(mx, v);
  }
  red[t] = mx;
  __syncthreads();
  for (int off = 128; off > 0; off >>= 1) {
    if (t < off) red[t] = fmaxf(red[t], red[t + off]);
    __syncthreads();
  }
  if (t == 0) *flag = (red[0] > 1000.f) ? 1 : 0;  // 1 => buffer is really f32
}

// ------------------- K1: build all generators -------------------
__global__ void build_gens(float2* slots, const void* inp, const void* w,
                           const int* flag) {
  int s = blockIdx.x;
  int t = threadIdx.x;
  if (t >= 100) return;
  int isf32 = *flag;
  int i = t / 10, j = t % 10;
  float2 val = make_float2(0.f, 0.f);
  if (s == SLOT_S0) {
    if (j == i + 2)      { float c = sqrtf((float)((i+1)*(i+2))); val.y = -0.25f*c; }
    else if (i == j + 2) { float c = sqrtf((float)((j+1)*(j+2))); val.y = -0.25f*c; }
  } else if (s < SLOT_SQ) {
    int k = s - SLOT_DM;
    float r = readv(inp, k, isf32);
    if (i == j + 1)      val.x =  r * sqrtf((float)(j+1));
    else if (j == i + 1) val.x = -r * sqrtf((float)(i+1));
  } else if (s < SLOT_DS) {
    int k = s - SLOT_SQ; int l = k >> 2; int m = k & 3;
    float r = readv(w, l*WSTRIDE + 16 + m, isf32);
    if (j == i + 2)      val.x =  0.5f*r*sqrtf((float)((i+1)*(i+2)));
    else if (i == j + 2) val.x = -0.5f*r*sqrtf((float)((j+1)*(j+2)));
  } else if (s < SLOT_BS) {
    int k = s - SLOT_DS; int l = k >> 2; int m = k & 3;
    float rd = readv(w, l*WSTRIDE + 36 + m, isf32);
    float ph = readv(w, l*WSTRIDE + 40 + m, isf32);
    float ar = rd * cosf(ph), ai = rd * sinf(ph);
    if (i == j + 1)      { float c = sqrtf((float)(j+1)); val.x =  ar*c; val.y = ai*c; }
    else if (j == i + 1) { float c = sqrtf((float)(i+1)); val.x = -ar*c; val.y = ai*c; }
  } else {
    int rel = s - SLOT_BS;
    int g = rel / 19; int N = rel % 19;
    int l = g / 12; int h = (g % 12) / 6; int p = g % 6;
    float th = readv(w, l*WSTRIDE + (h ? 20 : 0) + p, isf32);
    float ph = readv(w, l*WSTRIDE + (h ? 26 : 6) + p, isf32);
    int lo = max(0, N - 9), hi = min(9, N);
    int d = hi - lo + 1;
    if (i < d && j < d) {
      if (i == j + 1) {
        float c = sqrtf((float)((lo + j + 1) * (N - lo - j)));
        val.x = th * cosf(ph) * c; val.y = th * sinf(ph) * c;
      } else if (j == i + 1) {
        float c = sqrtf((float)((lo + i + 1) * (N - lo - i)));
        val.x = -th * cosf(ph) * c; val.y = th * sinf(ph) * c;
      }
    }
  }
  slots[(size_t)s * 100 + t] = val;
}

// ------------------- K2: generic expm (scaling-squaring + Taylor) -------------------
__global__ void expm_all(float2* slots) {
  __shared__ float2 T[100], P[100], R[100];
  __shared__ float rowsum[10];
  __shared__ int sshift;
  int s = blockIdx.x, t = threadIdx.x;
  int i = t / 10, j = t % 10;
  float2* G = slots + (size_t)s * 100;
  if (t < 100) T[t] = G[t];
  __syncthreads();
  if (t < 10) {
    float sum = 0.f;
    for (int c = 0; c < 10; ++c) { float2 z = T[t*10+c]; sum += fabsf(z.x) + fabsf(z.y); }
    rowsum[t] = sum;
  }
  __syncthreads();
  if (t == 0) {
    float nm = 0.f;
    for (int r = 0; r < 10; ++r) nm = fmaxf(nm, rowsum[r]);
    int sc = 0;
    if (!(nm < 1e6f)) sc = 0;
    else if (nm > 0.25f) sc = (int)ceilf(log2f(nm * 4.f));
    sshift = min(max(sc, 0), 40);
  }
  __syncthreads();
  int sh = sshift;
  float scl = ldexpf(1.f, -sh);
  if (t < 100) {
    float2 z = T[t]; z.x *= scl; z.y *= scl;
    T[t] = z; P[t] = z;
    R[t] = make_float2(z.x + (i == j ? 1.f : 0.f), z.y);
  }
  __syncthreads();
  for (int k = 2; k <= 12; ++k) {
    float2 acc = make_float2(0.f, 0.f);
    if (t < 100) {
      for (int c = 0; c < 10; ++c) {
        float2 a = P[i*10+c], b = T[c*10+j];
        acc.x += a.x*b.x - a.y*b.y;
        acc.y += a.x*b.y + a.y*b.x;
      }
      float inv = 1.f / (float)k;
      acc.x *= inv; acc.y *= inv;
    }
    __syncthreads();
    if (t < 100) { P[t] = acc; R[t].x += acc.x; R[t].y += acc.y; }
    __syncthreads();
  }
  for (int q = 0; q < sh; ++q) {
    float2 acc = make_float2(0.f, 0.f);
    if (t < 100) {
      for (int c = 0; c < 10; ++c) {
        float2 a = R[i*10+c], b = R[c*10+j];
        acc.x += a.x*b.x - a.y*b.y;
        acc.y += a.x*b.y + a.y*b.x;
      }
    }
    __syncthreads();
    if (t < 100) R[t] = acc;
    __syncthreads();
  }
  if (t < 100) G[t] = R[t];
}

// ------------------- K3: fused circuit — one block per batch, state in LDS -------------------
// Gate application uses photon-number anti-diagonal "lines": for a BS on modes
// (i,j), the 100 (n_i,n_j) values for fixed spectators split into 19 independent
// lines n_i+n_j=N of length d<=10. A thread owns whole lines -> loads to regs,
// applies the dxd block, writes back; no intra-gate hazard, one barrier/gate.
__global__ __launch_bounds__(1024) void fused_circuit(
    const float2* __restrict__ slots, const void* __restrict__ w,
    const int* __restrict__ flag, float* __restrict__ out)
{
  __shared__ float2 st[10000];   // 80 KB state
  __shared__ float2 psi[4][10];
  __shared__ float red[1024];
  const int b = blockIdx.x, t = threadIdx.x;
  const int isf32 = *flag;

  // mode element strides (state index e = n0*1000+n1*100+n2*10+n3)
  const int str_[4] = {1000, 100, 10, 1};
  // BS pair tables: pair p = (bi,bj), spectators ba<bb
  const int bi[6] = {0,0,0,1,1,2}, bj[6] = {1,2,3,2,3,3};
  const int ba[6] = {2,1,1,0,0,0}, bb[6] = {3,3,2,3,2,1};
  // single-gate spectator modes (ascending) for gate mode m
  const int s0_[4] = {1,0,0,0}, s1_[4] = {2,2,1,1}, s2_[4] = {3,3,3,2};

  // ---- initial product state ----
  if (t < 40) {
    int m = t / 10, r = t % 10;
    const float2* Dm = slots + (size_t)(SLOT_DM + b*4 + m) * 100;
    float2 acc = make_float2(0.f, 0.f);
    for (int c = 0; c < 10; ++c) {
      float2 a = Dm[r*10 + c];
      float2 v = slots[(size_t)c * 10];   // S0 column 0
      acc.x += a.x*v.x - a.y*v.y;
      acc.y += a.x*v.y + a.y*v.x;
    }
    psi[m][r] = acc;
  }
  __syncthreads();
  for (int e = t; e < 10000; e += 1024) {
    float2 z  = psi[0][e/1000];
    float2 w1 = psi[1][(e/100)%10];
    float2 r1 = make_float2(z.x*w1.x - z.y*w1.y, z.x*w1.y + z.y*w1.x);
    float2 w2 = psi[2][(e/10)%10];
    float2 r2 = make_float2(r1.x*w2.x - r1.y*w2.y, r1.x*w2.y + r1.y*w2.x);
    float2 w3 = psi[3][e%10];
    st[e] = make_float2(r2.x*w3.x - r2.y*w3.y, r2.x*w3.y + r2.y*w3.x);
  }
  __syncthreads();

  // ---- circuit ----
  for (int l = 0; l < NLAYERS; ++l) {
    for (int half = 0; half < 2; ++half) {
      // 6 beamsplitters (vph diag fused into p==5 output)
      for (int p = 0; p < 6; ++p) {
        int g = l*12 + half*6 + p;
        const float2* Ub = slots + (size_t)(SLOT_BS + g*19) * 100;
        int sI = str_[bi[p]], sJ = str_[bj[p]];
        int sA = str_[ba[p]], sB = str_[bb[p]];
        bool fuse = (p == 5);   // pair (2,3), spectators modes 0(slow),1(fast)
        float c0=0.f, c1=0.f, c2=0.f, c3=0.f;
        if (fuse) {
          int off = l*WSTRIDE + (half ? 32 : 12);
          c0 = readv(w, off+0, isf32); c1 = readv(w, off+1, isf32);
          c2 = readv(w, off+2, isf32); c3 = readv(w, off+3, isf32);
        }
        for (int line = t; line < 1900; line += 1024) {
          int N = line / 100, spec = line - N*100;
          int lo = max(0, N-9), d = min(9, N) - lo + 1;
          int base = (spec % 10)*sB + (spec / 10)*sA;
          int idx0 = base + lo*sI + (N - lo)*sJ;
          int step = sI - sJ;                    // > 0 (i < j)
          const float2* U = Ub + N*100;
          float2 v[10], o[10];
#pragma unroll
          for (int k = 0; k < 10; ++k) if (k < d) v[k] = st[idx0 + k*step];
#pragma unroll
          for (int r = 0; r < 10; ++r) if (r < d) {
            float2 acc = make_float2(0.f, 0.f);
#pragma unroll
            for (int k = 0; k < 10; ++k) if (k < d) {
              float2 u = U[r*10 + k];
              acc.x += u.x*v[k].x - u.y*v[k].y;
              acc.y += u.x*v[k].y + u.y*v[k].x;
            }
            o[r] = acc;
          }
          if (fuse) {
            // ang = c0*n0 + c1*n1 + c2*(lo+r) + c3*(N-lo-r)
            float angb = c0*(float)(spec/10) + c1*(float)(spec%10) + c3*(float)N;
            float dc = c2 - c3;
#pragma unroll
            for (int r = 0; r < 10; ++r) if (r < d) {
              float ang = angb + dc*(float)(lo + r);
              float sn, cs; sincosf(ang, &sn, &cs);
              float2 z = o[r];
              o[r] = make_float2(z.x*cs - z.y*sn, z.x*sn + z.y*cs);
            }
          }
#pragma unroll
          for (int r = 0; r < 10; ++r) if (r < d) st[idx0 + r*step] = o[r];
        }
        __syncthreads();
      }
      // 4 single-mode gates (squeeze half 0 / displace half 1, Kerr fused on last)
      for (int m = 0; m < 4; ++m) {
        int slot = (half == 0) ? (SLOT_SQ + l*4 + m) : (SLOT_DS + l*4 + m);
        const float2* U = slots + (size_t)slot * 100;
        int sM = str_[m];
        int spA = str_[s0_[m]], spB = str_[s1_[m]], spC = str_[s2_[m]];
        bool kerr = (half == 1 && m == 3);  // spectators modes 0,1,2 = q0,q1,q2
        float k0=0.f, k1=0.f, k2=0.f, k3=0.f;
        if (kerr) {
          int off = l*WSTRIDE + 44;
          k0 = readv(w, off+0, isf32); k1 = readv(w, off+1, isf32);
          k2 = readv(w, off+2, isf32); k3 = readv(w, off+3, isf32);
        }
        for (int line = t; line < 1000; line += 1024) {
          int q2 = line % 10, q1 = (line/10) % 10, q0 = line / 100;
          int base = q0*spA + q1*spB + q2*spC;
          float2 v[10], o[10];
#pragma unroll
          for (int k = 0; k < 10; ++k) v[k] = st[base + k*sM];
#pragma unroll
          for (int r = 0; r < 10; ++r) {
            float2 acc = make_float2(0.f, 0.f);
#pragma unroll
            for (int k = 0; k < 10; ++k) {
              float2 u = U[r*10 + k];
              acc.x += u.x*v[k].x - u.y*v[k].y;
              acc.y += u.x*v[k].y + u.y*v[k].x;
            }
            o[r] = acc;
          }
          if (kerr) {
            float angb = k0*(float)(q0*q0) + k1*(float)(q1*q1) + k2*(float)(q2*q2);
#pragma unroll
            for (int r = 0; r < 10; ++r) {
              float ang = angb + k3*(float)(r*r);
              float sn, cs; sincosf(ang, &sn, &cs);
              float2 z = o[r];
              o[r] = make_float2(z.x*cs - z.y*sn, z.x*sn + z.y*cs);
            }
          }
#pragma unroll
          for (int r = 0; r < 10; ++r) st[base + r*sM] = o[r];
        }
        __syncthreads();
      }
    }
  }

  // ---- photon-number expectations ----
  float a0 = 0.f, a1 = 0.f, a2 = 0.f, a3 = 0.f;
  for (int e = t; e < 10000; e += 1024) {
    float2 z = st[e];
    float pz = z.x*z.x + z.y*z.y;
    a0 += pz * (float)(e/1000);
    a1 += pz * (float)((e/100)%10);
    a2 += pz * (float)((e/10)%10);
    a3 += pz * (float)(e%10);
  }
  float vals[4] = {a0, a1, a2, a3};
  for (int m = 0; m < 4; ++m) {
    red[t] = vals[m];
    __syncthreads();
    for (int off = 512; off > 0; off >>= 1) {
      if (t < off) red[t] += red[t + off];
      __syncthreads();
    }
    if (t == 0) out[b*4 + m] = red[0];
    __syncthreads();
  }
}

extern "C" void kernel_launch(void* const* d_in, const int* in_sizes, int n_in,
                              void* d_out, int out_size, void* d_ws, size_t ws_size,
                              hipStream_t stream) {
  const void* inp = d_in[0];
  const void* w   = d_in[1];
  float* out = (float*)d_out;           // reference output dtype is float32
  int*    flag  = (int*)d_ws;           // 16-byte header
  float2* slots = (float2*)((char*)d_ws + 16);

  sniff_dtype<<<dim3(1), dim3(256), 0, stream>>>(inp, in_sizes[0], flag);
  build_gens<<<dim3(NSLOTS), dim3(128), 0, stream>>>(slots, inp, w, flag);
  expm_all<<<dim3(NSLOTS), dim3(128), 0, stream>>>(slots);
  fused_circuit<<<dim3(NB), dim3(1024), 0, stream>>>(slots, w, flag, out);
}